// Round 15
// baseline (438.952 us; speedup 1.0000x reference)
//
#include <hip/hip_runtime.h>

#define TT 512
#define DD 16
#define HH 30
#define LL 10
#define C  4                  // timesteps per chunk
#define TCH (TT / C)          // 128 chunks
#define RING 2                // slots per link (LDS-limited); drift +-1 chunk
#define GRP 16                // batches per group = MFMA N
#define NG 2                  // groups per block (dual-chain ILP)
#define BLOCKT (LL * 64)      // 640 threads, wave = layer
#define KPRE 2.885390081777927f   // 2*log2(e)

// LDS strides in halfs: per-(slot,group,cc) tile = 64 lanes x 8 halfs
#define CC_H   512
#define SLG_H  (C * CC_H)     // 2048
#define SL_H   (NG * SLG_H)   // 4096
#define LINK_H (RING * SL_H)  // 8192 halfs = 16 KB; 9 links = 147456 B

typedef _Float16 f16x8 __attribute__((ext_vector_type(8)));
typedef _Float16 h2    __attribute__((ext_vector_type(2)));
typedef float    f32x4 __attribute__((ext_vector_type(4)));

union U128 { uint4 u; f16x8 h; h2 p[4]; };

// sigma(d) = 1/(exp2(d)+1);  h = 1 - 2*sigma folded into consumer weights/bias.
__device__ __forceinline__ float sigma_e(float d) {
    const float e = __builtin_amdgcn_exp2f(d);
    return __builtin_amdgcn_rcpf(e + 1.0f);
}

// k-position -> natural neuron permutation (MFMA D == next B-own fragment).
__device__ __forceinline__ int nu_of(int k) {
    return 16 * ((k >> 2) & 1) + 4 * (k >> 3) + (k & 3);
}

__device__ __forceinline__ void wait_ge(unsigned* f, unsigned tgt) {
    while (__hip_atomic_load(f, __ATOMIC_ACQUIRE,
                             __HIP_MEMORY_SCOPE_WORKGROUP) < tgt)
        __builtin_amdgcn_s_sleep(1);
}

__global__ __launch_bounds__(BLOCKT) void rnn_dual2(
    const float* __restrict__ x,   const float* __restrict__ wi0,
    const float* __restrict__ wih, const float* __restrict__ whh,
    const float* __restrict__ bih, const float* __restrict__ bhh,
    const float* __restrict__ fcw, const float* __restrict__ fcb,
    float* __restrict__ out)
{
    extern __shared__ __align__(16) _Float16 link[]; // [LL-1][RING][NG][C][512h]
    __shared__ unsigned flg[2 * LL];  // [l]=produced(link l), [LL+l]=consumed(link l-1)

    const int tid  = threadIdx.x;
    const int l    = tid >> 6;        // wave == layer
    const int lane = tid & 63;
    const int n    = lane & 15;       // batch-in-group
    const int qq   = lane >> 4;       // k-slice / D row-group
    const int b0   = blockIdx.x * (GRP * NG);   // group A batches b0.., B b0+16..

    // ---- A-frags: sigma-folded (-2W), KPRE-prescaled; layer-0 x natural ----
    f16x8 wain[2], waown[2];
    #pragma unroll
    for (int tile = 0; tile < 2; ++tile) {
        const int j = 16 * tile + n;
        #pragma unroll
        for (int i = 0; i < 8; ++i) {
            const int kap = 8 * qq + i;
            const int nu  = nu_of(kap);
            float vi = 0.f, vo = 0.f;
            if (j < HH) {
                if (l == 0) { if (kap < DD) vi =  wi0[j * DD + kap]; }
                else        { if (nu  < HH) vi = -2.f * wih[(l - 1) * 900 + j * HH + nu]; }
                if (nu < HH) vo = -2.f * whh[l * 900 + j * HH + nu];
            }
            wain[tile][i]  = (_Float16)(vi * KPRE);
            waown[tile][i] = (_Float16)(vo * KPRE);
        }
    }
    // ---- bias C-init: KPRE*(b_ih + b_hh + rowsum(Whh) + (l>0 ? rowsum(Wih) : 0))
    f32x4 cb[2];
    #pragma unroll
    for (int tile = 0; tile < 2; ++tile)
        #pragma unroll
        for (int r = 0; r < 4; ++r) {
            const int j2 = 16 * tile + 4 * qq + r;
            float v = 0.f;
            if (j2 < HH) {
                v = bih[l * HH + j2] + bhh[l * HH + j2];
                for (int k = 0; k < HH; ++k) v += whh[l * 900 + j2 * HH + k];
                if (l > 0)
                    for (int k = 0; k < HH; ++k) v += wih[(l - 1) * 900 + j2 * HH + k];
            }
            cb[tile][r] = v * KPRE;
        }
    // ---- FC folded: out = (sum(fcw)+fcb) + sum(-2 fcw * sigma)
    float fcl[8];
    #pragma unroll
    for (int i = 0; i < 8; ++i) {
        const int nu = nu_of(8 * qq + i);
        fcl[i] = (nu < HH) ? -2.f * fcw[nu] : 0.f;
    }
    float fbv = fcb[0];
    for (int k = 0; k < HH; ++k) fbv += fcw[k];

    // LDS link bases (halfs); per-lane 16B slot at lane*8
    _Float16* lin_r = link + (l - 1) * LINK_H + lane * 8;  // valid for l>0
    _Float16* lin_w = link + l * LINK_H + lane * 8;        // valid for l<9

    // recurrent state x2 groups, sigma-encoded: sigma(h=0) = 0.5
    f16x8 bownA, bownB;
    #pragma unroll
    for (int i = 0; i < 8; ++i) { bownA[i] = (_Float16)0.5f; bownB[i] = (_Float16)0.5f; }

    if (tid < 2 * LL) flg[tid] = 0u;
    __syncthreads();                  // the only block-wide barrier

    // ---- wave-0 rolling x prefetch, both groups ----
    float4 xbA[C][2], xbB[C][2];
    const float4* x4 = (const float4*)x;
    const size_t xbA0 = (size_t)(b0 + n) * TT * 4;
    const size_t xbB0 = (size_t)(b0 + GRP + n) * TT * 4;
    if (l == 0 && qq < 2) {
        #pragma unroll
        for (int cc = 0; cc < C; ++cc) {          // chunk 0 raw
            xbA[cc][0] = x4[xbA0 + cc * 4 + 2 * qq];
            xbA[cc][1] = x4[xbA0 + cc * 4 + 2 * qq + 1];
            xbB[cc][0] = x4[xbB0 + cc * 4 + 2 * qq];
            xbB[cc][1] = x4[xbB0 + cc * 4 + 2 * qq + 1];
        }
    }

    for (int pb = 0; pb < TCH; pb += RING) {
        #pragma unroll
        for (int sl = 0; sl < RING; ++sl) {       // sl literal -> static offsets
            const int pt = pb + sl;

            // ---- producer slot-gate: slot held chunk pt-RING; consumer must
            //      have consumed it (cons >= pt-RING+1 = pt-1) ----
            if (l < LL - 1 && pt >= RING)
                wait_ge(&flg[LL + l + 1], (unsigned)(pt - RING + 1));

            // ---- acquire + load input chunk pt, both groups ----
            U128 binA[C], binB[C];
            if (l == 0) {
                #pragma unroll
                for (int cc = 0; cc < C; ++cc) {
                    if (qq < 2) {
                        float4 u = xbA[cc][0], v = xbA[cc][1];
                        binA[cc].p[0] = (h2)__builtin_amdgcn_cvt_pkrtz(u.x, u.y);
                        binA[cc].p[1] = (h2)__builtin_amdgcn_cvt_pkrtz(u.z, u.w);
                        binA[cc].p[2] = (h2)__builtin_amdgcn_cvt_pkrtz(v.x, v.y);
                        binA[cc].p[3] = (h2)__builtin_amdgcn_cvt_pkrtz(v.z, v.w);
                        u = xbB[cc][0]; v = xbB[cc][1];
                        binB[cc].p[0] = (h2)__builtin_amdgcn_cvt_pkrtz(u.x, u.y);
                        binB[cc].p[1] = (h2)__builtin_amdgcn_cvt_pkrtz(u.z, u.w);
                        binB[cc].p[2] = (h2)__builtin_amdgcn_cvt_pkrtz(v.x, v.y);
                        binB[cc].p[3] = (h2)__builtin_amdgcn_cvt_pkrtz(v.z, v.w);
                        if (pt + 1 < TCH) {        // rolling refill, 1 chunk ahead
                            const int tn = (pt + 1) * C + cc;
                            xbA[cc][0] = x4[xbA0 + tn * 4 + 2 * qq];
                            xbA[cc][1] = x4[xbA0 + tn * 4 + 2 * qq + 1];
                            xbB[cc][0] = x4[xbB0 + tn * 4 + 2 * qq];
                            xbB[cc][1] = x4[xbB0 + tn * 4 + 2 * qq + 1];
                        }
                    } else {
                        binA[cc].u = uint4{0u, 0u, 0u, 0u};
                        binB[cc].u = uint4{0u, 0u, 0u, 0u};
                    }
                }
            } else {
                wait_ge(&flg[l - 1], (unsigned)(pt + 1));      // producer done
                #pragma unroll
                for (int cc = 0; cc < C; ++cc) {
                    binA[cc].u = *(const uint4*)(lin_r + (sl * NG + 0) * SLG_H + cc * CC_H);
                    binB[cc].u = *(const uint4*)(lin_r + (sl * NG + 1) * SLG_H + cc * CC_H);
                }
            }

            // ---- input-side MFMAs, both groups: independent, issue early ----
            f32x4 dpA0[C], dpA1[C], dpB0[C], dpB1[C];
            #pragma unroll
            for (int cc = 0; cc < C; ++cc) {
                dpA0[cc] = __builtin_amdgcn_mfma_f32_16x16x32_f16(wain[0], binA[cc].h, cb[0], 0, 0, 0);
                dpB0[cc] = __builtin_amdgcn_mfma_f32_16x16x32_f16(wain[0], binB[cc].h, cb[0], 0, 0, 0);
                dpA1[cc] = __builtin_amdgcn_mfma_f32_16x16x32_f16(wain[1], binA[cc].h, cb[1], 0, 0, 0);
                dpB1[cc] = __builtin_amdgcn_mfma_f32_16x16x32_f16(wain[1], binB[cc].h, cb[1], 0, 0, 0);
            }
            // publish consumption (release orders our ds_reads)
            if (l > 0 && lane == 0)
                __hip_atomic_store(&flg[LL + l], (unsigned)(pt + 1),
                                   __ATOMIC_RELEASE, __HIP_MEMORY_SCOPE_WORKGROUP);

            // ---- dual serial own-chains, interleaved: B's ops fill A's
            //      mfma/exp2 latency and vice versa ----
            #pragma unroll
            for (int cc = 0; cc < C; ++cc) {
                const f32x4 dA0 = __builtin_amdgcn_mfma_f32_16x16x32_f16(waown[0], bownA, dpA0[cc], 0, 0, 0);
                const f32x4 dB0 = __builtin_amdgcn_mfma_f32_16x16x32_f16(waown[0], bownB, dpB0[cc], 0, 0, 0);
                const f32x4 dA1 = __builtin_amdgcn_mfma_f32_16x16x32_f16(waown[1], bownA, dpA1[cc], 0, 0, 0);
                const f32x4 dB1 = __builtin_amdgcn_mfma_f32_16x16x32_f16(waown[1], bownB, dpB1[cc], 0, 0, 0);
                U128 uA, uB;
                uA.p[0] = (h2)__builtin_amdgcn_cvt_pkrtz(sigma_e(dA0[0]), sigma_e(dA0[1]));
                uB.p[0] = (h2)__builtin_amdgcn_cvt_pkrtz(sigma_e(dB0[0]), sigma_e(dB0[1]));
                uA.p[1] = (h2)__builtin_amdgcn_cvt_pkrtz(sigma_e(dA0[2]), sigma_e(dA0[3]));
                uB.p[1] = (h2)__builtin_amdgcn_cvt_pkrtz(sigma_e(dB0[2]), sigma_e(dB0[3]));
                uA.p[2] = (h2)__builtin_amdgcn_cvt_pkrtz(sigma_e(dA1[0]), sigma_e(dA1[1]));
                uB.p[2] = (h2)__builtin_amdgcn_cvt_pkrtz(sigma_e(dB1[0]), sigma_e(dB1[1]));
                uA.p[3] = (h2)__builtin_amdgcn_cvt_pkrtz(sigma_e(dA1[2]), sigma_e(dA1[3]));
                uB.p[3] = (h2)__builtin_amdgcn_cvt_pkrtz(sigma_e(dB1[2]), sigma_e(dB1[3]));
                bownA = uA.h;
                bownB = uB.h;
                if (l < LL - 1) {
                    *(uint4*)(lin_w + (sl * NG + 0) * SLG_H + cc * CC_H) = uA.u;
                    *(uint4*)(lin_w + (sl * NG + 1) * SLG_H + cc * CC_H) = uB.u;
                }
            }
            // publish production (release drains our ds_writes)
            if (l < LL - 1 && lane == 0)
                __hip_atomic_store(&flg[l], (unsigned)(pt + 1),
                                   __ATOMIC_RELEASE, __HIP_MEMORY_SCOPE_WORKGROUP);
        }
    }

    // ---- FC on sigma_9(T-1), both groups ----
    if (l == LL - 1) {
        float vA = 0.f, vB = 0.f;
        #pragma unroll
        for (int i = 0; i < 8; ++i) {
            vA = fmaf((float)bownA[i], fcl[i], vA);
            vB = fmaf((float)bownB[i], fcl[i], vB);
        }
        vA += __shfl_xor(vA, 16);  vB += __shfl_xor(vB, 16);
        vA += __shfl_xor(vA, 32);  vB += __shfl_xor(vB, 32);
        if (qq == 0) {
            out[b0 + n]       = vA + fbv;
            out[b0 + GRP + n] = vB + fbv;
        }
    }
}

extern "C" void kernel_launch(void* const* d_in, const int* in_sizes, int n_in,
                              void* d_out, int out_size, void* d_ws, size_t ws_size,
                              hipStream_t stream) {
    const float* x   = (const float*)d_in[0];
    const float* wi0 = (const float*)d_in[1];
    const float* wih = (const float*)d_in[2];
    const float* whh = (const float*)d_in[3];
    const float* bih = (const float*)d_in[4];
    const float* bhh = (const float*)d_in[5];
    const float* fcw = (const float*)d_in[6];
    const float* fcb = (const float*)d_in[7];
    float* out = (float*)d_out;

    const size_t lds_bytes = (size_t)(LL - 1) * LINK_H * sizeof(_Float16); // 147456 B
    hipFuncSetAttribute((const void*)rnn_dual2,
                        hipFuncAttributeMaxDynamicSharedMemorySize,
                        (int)lds_bytes);

    rnn_dual2<<<1024 / (GRP * NG), BLOCKT, lds_bytes, stream>>>(
        x, wi0, wih, whh, bih, bhh, fcw, fcb, out);
}

// Round 16
// 202.154 us; speedup vs baseline: 2.1714x; 2.1714x over previous
//
#include <hip/hip_runtime.h>

#define TT 512
#define DD 16
#define HH 30
#define LL 10
#define CHK 8                 // timesteps per chunk (sync granularity)
#define HC  4                 // timesteps per half (inner body = R13's)
#define NCH (TT / CHK)        // 64 chunks
#define RING 2                // slots per link; slack = 8..16 timesteps
#define GRP 16                // batches per block = MFMA N
#define BLOCKT (LL * 64)      // 640 threads, wave = layer
#define KPRE 2.885390081777927f   // 2*log2(e)

// LDS strides in halfs: per-(slot,half,cc) tile = 64 lanes x 8 halfs
#define CC_H   512
#define HALF_H (HC * CC_H)    // 2048
#define SL_H   (CHK * CC_H)   // 4096
#define LINK_H (RING * SL_H)  // 8192 halfs = 16 KB; 9 links = 147456 B

typedef _Float16 f16x8 __attribute__((ext_vector_type(8)));
typedef _Float16 h2    __attribute__((ext_vector_type(2)));
typedef float    f32x4 __attribute__((ext_vector_type(4)));

union U128 { uint4 u; f16x8 h; h2 p[4]; };

// sigma(d) = 1/(exp2(d)+1);  h = 1 - 2*sigma folded into consumer weights/bias.
__device__ __forceinline__ float sigma_e(float d) {
    const float e = __builtin_amdgcn_exp2f(d);
    return __builtin_amdgcn_rcpf(e + 1.0f);
}

// k-position -> natural neuron permutation (MFMA D == next B-own fragment).
__device__ __forceinline__ int nu_of(int k) {
    return 16 * ((k >> 2) & 1) + 4 * (k >> 3) + (k & 3);
}

__device__ __forceinline__ void wait_ge(unsigned* f, unsigned tgt) {
    while (__hip_atomic_load(f, __ATOMIC_ACQUIRE,
                             __HIP_MEMORY_SCOPE_WORKGROUP) < tgt)
        __builtin_amdgcn_s_sleep(1);
}

// Hand-rolled release: order our LDS ops before the LDS flag store, and
// NOTHING else -- never drains vmcnt (wave-0 global prefetch stays in flight).
__device__ __forceinline__ void publish(unsigned* f, unsigned v) {
    __builtin_amdgcn_sched_barrier(0);
    asm volatile("s_waitcnt lgkmcnt(0)" ::: "memory");
    __hip_atomic_store(f, v, __ATOMIC_RELAXED, __HIP_MEMORY_SCOPE_WORKGROUP);
}

__global__ __launch_bounds__(BLOCKT) void rnn_c8(
    const float* __restrict__ x,   const float* __restrict__ wi0,
    const float* __restrict__ wih, const float* __restrict__ whh,
    const float* __restrict__ bih, const float* __restrict__ bhh,
    const float* __restrict__ fcw, const float* __restrict__ fcb,
    float* __restrict__ out)
{
    extern __shared__ __align__(16) _Float16 link[]; // [LL-1][RING][CHK][512h]
    __shared__ unsigned flg[2 * LL];  // [l]=produced(link l), [LL+l]=consumed(link l-1)

    const int tid  = threadIdx.x;
    const int l    = tid >> 6;        // wave == layer
    const int lane = tid & 63;
    const int n    = lane & 15;       // batch-in-group
    const int qq   = lane >> 4;       // k-slice / D row-group
    const int b0   = blockIdx.x * GRP;

    // ---- A-frags: sigma-folded (-2W), KPRE-prescaled; layer-0 x natural ----
    f16x8 wain[2], waown[2];
    #pragma unroll
    for (int tile = 0; tile < 2; ++tile) {
        const int j = 16 * tile + n;
        #pragma unroll
        for (int i = 0; i < 8; ++i) {
            const int kap = 8 * qq + i;
            const int nu  = nu_of(kap);
            float vi = 0.f, vo = 0.f;
            if (j < HH) {
                if (l == 0) { if (kap < DD) vi =  wi0[j * DD + kap]; }
                else        { if (nu  < HH) vi = -2.f * wih[(l - 1) * 900 + j * HH + nu]; }
                if (nu < HH) vo = -2.f * whh[l * 900 + j * HH + nu];
            }
            wain[tile][i]  = (_Float16)(vi * KPRE);
            waown[tile][i] = (_Float16)(vo * KPRE);
        }
    }
    // ---- bias C-init: KPRE*(b_ih + b_hh + rowsum(Whh) + (l>0 ? rowsum(Wih) : 0))
    f32x4 cb[2];
    #pragma unroll
    for (int tile = 0; tile < 2; ++tile)
        #pragma unroll
        for (int r = 0; r < 4; ++r) {
            const int j2 = 16 * tile + 4 * qq + r;
            float v = 0.f;
            if (j2 < HH) {
                v = bih[l * HH + j2] + bhh[l * HH + j2];
                for (int k = 0; k < HH; ++k) v += whh[l * 900 + j2 * HH + k];
                if (l > 0)
                    for (int k = 0; k < HH; ++k) v += wih[(l - 1) * 900 + j2 * HH + k];
            }
            cb[tile][r] = v * KPRE;
        }
    // ---- FC folded: out = (sum(fcw)+fcb) + sum(-2 fcw * sigma)
    float fcl[8];
    #pragma unroll
    for (int i = 0; i < 8; ++i) {
        const int nu = nu_of(8 * qq + i);
        fcl[i] = (nu < HH) ? -2.f * fcw[nu] : 0.f;
    }
    float fbv = fcb[0];
    for (int k = 0; k < HH; ++k) fbv += fcw[k];

    // ---- wave-0 x prefetch: xb = raw float4 for the NEXT 4-timestep half ----
    float4 xb[HC][2];
    const float4* x4 = (const float4*)x;
    const size_t xbase = (size_t)(b0 + n) * TT * 4;
    if (l == 0 && qq < 2) {
        #pragma unroll
        for (int cc = 0; cc < HC; ++cc) {          // half 0 (t = 0..3)
            xb[cc][0] = x4[xbase + cc * 4 + 2 * qq];
            xb[cc][1] = x4[xbase + cc * 4 + 2 * qq + 1];
        }
    }

    // LDS link bases (halfs); per-lane 16B slot at lane*8
    _Float16* lin_r = link + (l - 1) * LINK_H + lane * 8;  // valid for l>0
    _Float16* lin_w = link + l * LINK_H + lane * 8;        // valid for l<9

    // recurrent state: sigma-encoded, sigma(h=0) = 0.5
    f16x8 bown;
    #pragma unroll
    for (int i = 0; i < 8; ++i) bown[i] = (_Float16)0.5f;

    if (tid < 2 * LL) flg[tid] = 0u;
    __syncthreads();                  // the only block-wide barrier

    for (int pb = 0; pb < NCH; pb += RING) {
        #pragma unroll
        for (int sl = 0; sl < RING; ++sl) {       // sl literal -> static offsets
            const int pt = pb + sl;

            // producer slot-gate: slot sl held chunk pt-RING; consumer must
            // have consumed it (cons >= pt-RING+1)
            if (l < LL - 1 && pt >= RING)
                wait_ge(&flg[LL + l + 1], (unsigned)(pt - RING + 1));
            // consumer chunk poll: producer finished chunk pt entirely
            if (l > 0)
                wait_ge(&flg[l - 1], (unsigned)(pt + 1));

            #pragma unroll
            for (int h = 0; h < 2; ++h) {         // two R13-style 4-cc halves
                // ---- load/convert input half ----
                U128 binu[HC];
                if (l == 0) {
                    #pragma unroll
                    for (int cc = 0; cc < HC; ++cc) {
                        if (qq < 2) {
                            const float4 u = xb[cc][0], v = xb[cc][1];
                            binu[cc].p[0] = (h2)__builtin_amdgcn_cvt_pkrtz(u.x, u.y);
                            binu[cc].p[1] = (h2)__builtin_amdgcn_cvt_pkrtz(u.z, u.w);
                            binu[cc].p[2] = (h2)__builtin_amdgcn_cvt_pkrtz(v.x, v.y);
                            binu[cc].p[3] = (h2)__builtin_amdgcn_cvt_pkrtz(v.z, v.w);
                            const int gh = pt * 2 + h + 1;     // next half index
                            if (gh < TT / HC) {                // rolling refill
                                const int tn = gh * HC + cc;
                                xb[cc][0] = x4[xbase + tn * 4 + 2 * qq];
                                xb[cc][1] = x4[xbase + tn * 4 + 2 * qq + 1];
                            }
                        } else {
                            binu[cc].u = uint4{0u, 0u, 0u, 0u};
                        }
                    }
                } else {
                    #pragma unroll
                    for (int cc = 0; cc < HC; ++cc)
                        binu[cc].u = *(const uint4*)(lin_r + sl * SL_H + h * HALF_H
                                                     + cc * CC_H);
                }

                // ---- input-side MFMAs: independent, issue early ----
                f32x4 dp0[HC], dp1[HC];
                #pragma unroll
                for (int cc = 0; cc < HC; ++cc) {
                    dp0[cc] = __builtin_amdgcn_mfma_f32_16x16x32_f16(wain[0], binu[cc].h, cb[0], 0, 0, 0);
                    dp1[cc] = __builtin_amdgcn_mfma_f32_16x16x32_f16(wain[1], binu[cc].h, cb[1], 0, 0, 0);
                }
                // publish consumption once per chunk, after ALL 8 reads issued
                // (the publish's lgkm drain covers them)
                if (h == 1 && l > 0 && lane == 0)
                    publish(&flg[LL + l], (unsigned)(pt + 1));

                // ---- serial own-chain: mfma -> sigma -> pack -> ds_write ----
                #pragma unroll
                for (int cc = 0; cc < HC; ++cc) {
                    const f32x4 d0 = __builtin_amdgcn_mfma_f32_16x16x32_f16(waown[0], bown, dp0[cc], 0, 0, 0);
                    const f32x4 d1 = __builtin_amdgcn_mfma_f32_16x16x32_f16(waown[1], bown, dp1[cc], 0, 0, 0);
                    U128 uu;
                    uu.p[0] = (h2)__builtin_amdgcn_cvt_pkrtz(sigma_e(d0[0]), sigma_e(d0[1]));
                    uu.p[1] = (h2)__builtin_amdgcn_cvt_pkrtz(sigma_e(d0[2]), sigma_e(d0[3]));
                    uu.p[2] = (h2)__builtin_amdgcn_cvt_pkrtz(sigma_e(d1[0]), sigma_e(d1[1]));
                    uu.p[3] = (h2)__builtin_amdgcn_cvt_pkrtz(sigma_e(d1[2]), sigma_e(d1[3]));
                    bown = uu.h;
                    if (l < LL - 1)
                        *(uint4*)(lin_w + sl * SL_H + h * HALF_H + cc * CC_H) = uu.u;
                }
            }
            // publish production once per chunk (lgkm drain covers ds_writes)
            if (l < LL - 1 && lane == 0)
                publish(&flg[l], (unsigned)(pt + 1));
        }
    }

    // ---- FC on sigma_9(T-1): out = (sum fcw + fcb) + sum(-2 fcw * sigma) ----
    if (l == LL - 1) {
        float v = 0.f;
        #pragma unroll
        for (int i = 0; i < 8; ++i) v = fmaf((float)bown[i], fcl[i], v);
        v += __shfl_xor(v, 16);      // combine the four qq k-slices
        v += __shfl_xor(v, 32);
        if (qq == 0) out[b0 + n] = v + fbv;
    }
}

extern "C" void kernel_launch(void* const* d_in, const int* in_sizes, int n_in,
                              void* d_out, int out_size, void* d_ws, size_t ws_size,
                              hipStream_t stream) {
    const float* x   = (const float*)d_in[0];
    const float* wi0 = (const float*)d_in[1];
    const float* wih = (const float*)d_in[2];
    const float* whh = (const float*)d_in[3];
    const float* bih = (const float*)d_in[4];
    const float* bhh = (const float*)d_in[5];
    const float* fcw = (const float*)d_in[6];
    const float* fcb = (const float*)d_in[7];
    float* out = (float*)d_out;

    const size_t lds_bytes = (size_t)(LL - 1) * LINK_H * sizeof(_Float16); // 147456 B
    hipFuncSetAttribute((const void*)rnn_c8,
                        hipFuncAttributeMaxDynamicSharedMemorySize,
                        (int)lds_bytes);

    rnn_c8<<<1024 / GRP, BLOCKT, lds_bytes, stream>>>(x, wi0, wih, whh,
                                                      bih, bhh, fcw, fcb, out);
}